// Round 1
// baseline (663.060 us; speedup 1.0000x reference)
//
#include <hip/hip_runtime.h>
#include <hip/hip_bf16.h>

#define DFEAT 64
#define EPSBN 1e-5f

// ---------------- degree accumulation ----------------
__global__ void deg_kernel(const int* __restrict__ src, const int* __restrict__ dst,
                           float* __restrict__ deg_out, float* __restrict__ deg_in, int E) {
    int e = blockIdx.x * blockDim.x + threadIdx.x;
    if (e < E) {
        atomicAdd(&deg_out[src[e]], 1.0f);
        atomicAdd(&deg_in[dst[e]], 1.0f);
    }
}

// ---------------- scatter-add SpMM: agg[dst] += x[src] * norm_src ----------------
// one 64-lane wave per edge, lane = feature
__global__ __launch_bounds__(256) void scatter_kernel(
        const float* __restrict__ x, const int* __restrict__ src,
        const int* __restrict__ dst, const float* __restrict__ deg_out,
        float* __restrict__ agg, int E) {
    int lane = threadIdx.x & 63;
    int e = blockIdx.x * 4 + (threadIdx.x >> 6);
    if (e < E) {
        int s = src[e];
        int d = dst[e];
        float ns = rsqrtf(fmaxf(deg_out[s], 1.0f));
        atomicAdd(&agg[(size_t)d * DFEAT + lane], x[(size_t)s * DFEAT + lane] * ns);
    }
}

// ---------------- y = (agg * norm_dst) @ W + b, fused BN-stat accumulation ----------------
// one wave per row, lane = output column; W staged in LDS
__global__ __launch_bounds__(256) void gemm_bn_kernel(
        const float* __restrict__ agg, const float* __restrict__ deg_in,
        const float* __restrict__ W, const float* __restrict__ bvec,
        float* __restrict__ y, float* __restrict__ sums, float* __restrict__ sumsq,
        int n_nodes, int nblocks) {
    __shared__ float Wlds[DFEAT * DFEAT];
    __shared__ float arow[4][DFEAT];
    __shared__ float red_s[4][DFEAT];
    __shared__ float red_q[4][DFEAT];

    int tid = threadIdx.x;
    int wave = tid >> 6;
    int lane = tid & 63;

    for (int i = tid; i < DFEAT * DFEAT; i += 256) Wlds[i] = W[i];
    __syncthreads();

    float bc = bvec[lane];
    float bsum = 0.f, bsq = 0.f;

    for (int r0 = blockIdx.x * 4; r0 < n_nodes; r0 += nblocks * 4) {
        int r = r0 + wave;
        if (r < n_nodes) {
            float nd = rsqrtf(fmaxf(deg_in[r], 1.0f));
            // wave-local LDS exchange (no barrier needed: same wave writes & reads)
            arow[wave][lane] = agg[(size_t)r * DFEAT + lane] * nd;
            float acc = 0.f;
            #pragma unroll 16
            for (int k = 0; k < DFEAT; ++k) {
                acc += arow[wave][k] * Wlds[k * DFEAT + lane];
            }
            acc += bc;
            y[(size_t)r * DFEAT + lane] = acc;
            bsum += acc;
            bsq += acc * acc;
        }
    }

    red_s[wave][lane] = bsum;
    red_q[wave][lane] = bsq;
    __syncthreads();
    if (wave == 0) {
        float s = red_s[0][lane] + red_s[1][lane] + red_s[2][lane] + red_s[3][lane];
        float q = red_q[0][lane] + red_q[1][lane] + red_q[2][lane] + red_q[3][lane];
        atomicAdd(&sums[lane], s);
        atomicAdd(&sumsq[lane], q);
    }
}

// ---------------- BN (batch stats) + ReLU + residual, in place on y ----------------
__global__ void bn_relu_res_kernel(const float* __restrict__ x,
                                   const float* __restrict__ sums,
                                   const float* __restrict__ sumsq,
                                   const float* __restrict__ gamma,
                                   const float* __restrict__ beta,
                                   float* __restrict__ y, int total, float inv_n) {
    int i = blockIdx.x * blockDim.x + threadIdx.x;
    if (i < total) {
        int c = i & (DFEAT - 1);
        float mean = sums[c] * inv_n;
        float var = sumsq[c] * inv_n - mean * mean;
        float inv = rsqrtf(var + EPSBN);
        float v = (y[i] - mean) * inv * gamma[c] + beta[c];
        v = fmaxf(v, 0.f);
        y[i] = x[i] + v;
    }
}

extern "C" void kernel_launch(void* const* d_in, const int* in_sizes, int n_in,
                              void* d_out, int out_size, void* d_ws, size_t ws_size,
                              hipStream_t stream) {
    const float* x     = (const float*)d_in[0];
    const int*   src   = (const int*)d_in[1];
    const int*   dst   = (const int*)d_in[2];
    const float* W     = (const float*)d_in[3];
    const float* bvec  = (const float*)d_in[4];
    const float* gamma = (const float*)d_in[5];
    const float* beta  = (const float*)d_in[6];
    float* out = (float*)d_out;

    const int n_nodes = in_sizes[0] / DFEAT;
    const int E = in_sizes[1];

    float* ws = (float*)d_ws;
    float* deg_out = ws;                    // n_nodes
    float* deg_in  = ws + n_nodes;          // n_nodes
    float* agg     = ws + 2 * (size_t)n_nodes;          // n_nodes * 64
    float* sums    = agg + (size_t)n_nodes * DFEAT;     // 64
    float* sumsq   = sums + DFEAT;                      // 64

    size_t zero_bytes = (2 * (size_t)n_nodes + (size_t)n_nodes * DFEAT + 2 * DFEAT) * sizeof(float);
    hipMemsetAsync(d_ws, 0, zero_bytes, stream);

    deg_kernel<<<(E + 255) / 256, 256, 0, stream>>>(src, dst, deg_out, deg_in, E);

    scatter_kernel<<<(E + 3) / 4, 256, 0, stream>>>(x, src, dst, deg_out, agg, E);

    const int nblk = 1024;
    gemm_bn_kernel<<<nblk, 256, 0, stream>>>(agg, deg_in, W, bvec, out, sums, sumsq,
                                             n_nodes, nblk);

    int total = n_nodes * DFEAT;
    bn_relu_res_kernel<<<(total + 255) / 256, 256, 0, stream>>>(
        x, sums, sumsq, gamma, beta, out, total, 1.0f / (float)n_nodes);
}